// Round 1
// baseline (380.384 us; speedup 1.0000x reference)
//
#include <hip/hip_runtime.h>
#include <cstdint>
#include <cstddef>

// Problem constants (from reference)
#define D_MODEL   1024
#define STATE_DIM 512
#define BATCH     4
#define SEQ_LEN   8192
#define M_TOTAL   (BATCH * SEQ_LEN)   // 32768

typedef unsigned short ushort_t;
typedef __attribute__((ext_vector_type(8))) __bf16 bf16x8;
typedef __attribute__((ext_vector_type(4))) float  f32x4;

// ---------- helpers ----------

__device__ inline ushort_t f2bf(float f) {
  union { float f; uint32_t u; } v; v.f = f;
  uint32_t u = v.u;
  uint32_t r = (u + 0x7FFFu + ((u >> 16) & 1u)) >> 16;  // RNE
  return (ushort_t)r;
}

__device__ inline float bf2f(ushort_t b) {
  union { uint32_t u; float f; } v; v.u = ((uint32_t)b) << 16;
  return v.f;
}

// async global->LDS, 16B per lane. LDS dest = wave-uniform base + lane*16.
__device__ inline void llds16(const void* g, void* l) {
  __builtin_amdgcn_global_load_lds(
      (__attribute__((address_space(1))) void*)(void*)g,
      (__attribute__((address_space(3))) void*)l,
      16, 0, 0);
}

// ---------- fp32 -> bf16 conversion (vectorized) ----------

__global__ void convert_f32_bf16(const float* __restrict__ in,
                                 ushort_t* __restrict__ out, int n4) {
  int i = blockIdx.x * blockDim.x + threadIdx.x;
  if (i >= n4) return;
  const float4 v = ((const float4*)in)[i];
  ushort4 o;
  o.x = f2bf(v.x); o.y = f2bf(v.y); o.z = f2bf(v.z); o.w = f2bf(v.w);
  ((ushort4*)out)[i] = o;
}

// ---------- eigenvalues ----------
// lambda_j = (1 - i*w_j)/(1 + i*w_j), w = Im(FFT(a_full)).
// lam layout: [0:512) re, [512:1024) im, [1024:1536) re(lam^CLEN), [1536:2048) im(lam^CLEN)

#define NCHUNK 128
#define CLEN   64
#define SOFF   (BATCH * NCHUNK * STATE_DIM)  // 262144: im-plane offset in S/Hin

__global__ __launch_bounds__(64)
void eigen_kernel(const float* __restrict__ a_params, float* __restrict__ lam) {
  const int k = blockIdx.x;
  const int l = threadIdx.x;
  const float c = 6.283185307179586f / 512.0f;
  float om = 0.f;
#pragma unroll
  for (int s = 0; s < 8; ++s) {
    const int n = s * 64 + l;
    float v = 0.f;
    if (n >= 1 && n <= STATE_DIM / 2)      v = a_params[n - 1];
    else if (n > STATE_DIM / 2)            v = -a_params[STATE_DIM - n];
    const int p = (k * n) & 511;            // exact integer phase reduction
    om -= v * sinf(c * (float)p);
  }
#pragma unroll
  for (int off = 32; off; off >>= 1) om += __shfl_down(om, off);
  if (l == 0) {
    const float d  = 1.f / (1.f + om * om);
    const float lr = (1.f - om * om) * d;
    const float li = -2.f * om * d;         // |lambda| == 1 analytically
    double th = atan2((double)li, (double)lr) * (double)CLEN;
    lam[k]        = lr;
    lam[512 + k]  = li;
    lam[1024 + k] = (float)cos(th);
    lam[1536 + k] = (float)sin(th);
  }
}

// ---------- 256x256 8-phase bf16 MFMA GEMM (B^T): out[m][n] = sum_k A[m][k]*Bw[n][k] ----
// Port of the verified 256² 8-phase schedule (learn_hip m201): BK=64, 8 waves
// (2M x 4N), 128 KiB LDS (2 K-tile slots x (A 32KB + B 32KB)), per-wave output
// 128x64 as 8x4 frags of 16x16x32 MFMA.
//
// Per K-tile kt (slot s = kt&1), 4 phases; quadrant walk (0,0)->(0,1)->(1,1)->(1,0):
//   P1: ds_read A[mi0-3](8xb128) + B[ni0-1]->b0 (4) | bar | 16 MFMA | bar
//   P2: ds_read B[ni2-3]->b1 (4)                    | bar | 16 MFMA | bar
//   P3: ds_read A[mi4-7] (8); STAGE B-halves(kt+2)  | bar | 16 MFMA | bar
//   P4: STAGE A-halves(kt+2) | bar | 16 MFMA; vmcnt(8) | bar
// Residency ledger: at P4's vmcnt(8), the 8 newest loads are this K-tile's
// stages (kt+2 data) -> everything for kt+1 (staged during kt-1) is resident.
// Write-after-read: a half-tile is restaged >=1 full barrier after its last
// ds_read completed (reads complete before the consuming MFMA issues, which
// precedes that phase's closing barrier). Main loop never drains vmcnt to 0;
// kt=NIT-2 drains vmcnt(0) (epilogue of the pipeline).
//
// T2 st_16x32 swizzle, both-sides (rule #21): LDS dest stays linear
// (global_load_lds requirement); the GLOBAL source column is pre-permuted by
// the involution byte^=((byte>>9)&1)<<5 (here: chunk ^= ((row>>2)&1)<<1), and
// the ds_read applies the same XOR. T1 bijective XCD swizzle (nwg%8==0 for
// both shapes). T5 setprio(1) around each MFMA cluster.

template <int QM, int QN>
__device__ __forceinline__ void mfma_quad(f32x4 (&acc)[8][4],
                                          const bf16x8 (&a)[4][2],
                                          const bf16x8 (&b)[2][2]) {
#pragma unroll
  for (int mi = 0; mi < 4; ++mi)
#pragma unroll
    for (int ni = 0; ni < 2; ++ni)
#pragma unroll
      for (int ks = 0; ks < 2; ++ks)
        acc[QM * 4 + mi][QN * 2 + ni] = __builtin_amdgcn_mfma_f32_16x16x32_bf16(
            a[mi][ks], b[ni][ks], acc[QM * 4 + mi][QN * 2 + ni], 0, 0, 0);
}

template <int NFR>
__device__ __forceinline__ void load_frags(bf16x8 (&dst)[NFR][2], const char* base) {
#pragma unroll
  for (int i = 0; i < NFR; ++i)
#pragma unroll
    for (int ks = 0; ks < 2; ++ks)
      dst[i][ks] = *(const bf16x8*)(base + i * 2048 + ks * 64);
}

template <int KDIM, int NDIM, bool OUT_BF16, bool FUSE_SKIP>
__global__ __launch_bounds__(512, 2)
void gemm256(const ushort_t* __restrict__ A,       // M x KDIM  (bf16)
             const ushort_t* __restrict__ Bw,      // NDIM x KDIM (bf16)
             void* __restrict__ outv,              // M x NDIM
             const ushort_t* __restrict__ skip_b,  // M x NDIM (bf16) or null
             const float* __restrict__ Dvec) {     // NDIM or null
  extern __shared__ char sm[];                     // 131072 B dynamic
  constexpr int NIT = KDIM / 64;                   // K-tiles of 64
  const int tid    = threadIdx.x;
  const int wave   = tid >> 6, lane = tid & 63;
  const int lane16 = lane & 15, quad = lane >> 4;
  const int wm = wave >> 2, wn = wave & 3;         // 2 x 4 wave grid

  // T1: bijective XCD-aware block swizzle (nwg % 8 == 0 for both shapes)
  const int gx   = gridDim.x;
  const int nwg  = gx * gridDim.y;
  const int bid0 = blockIdx.y * gx + blockIdx.x;
  const int bid  = (bid0 & 7) * (nwg >> 3) + (bid0 >> 3);
  const int row0 = (bid % gx) * 256;
  const int col0 = (bid / gx) * 256;

  // frag-read addressing: within a 16KB half: byte = r*128 + chunk*16,
  // chunk = (ks*4 + quad) ^ (((r>>2)&1)<<1); r bit2 == lane16 bit2 -> lane const
  const int xr     = ((lane16 >> 2) & 1) << 1;
  const int lfrag  = lane16 * 128 + ((quad ^ xr) * 16);
  const int aRegion = wm * 16384;                               // A half = wave's wm
  const int bRegion = 32768 + (wn >> 1) * 16384 + (wn & 1) * 8192;

  // staging: lane covers (row = q*64 + tid/8, chunk pre-swizzled to match reads)
  const int srow = tid >> 3;                                    // 0..63
  const int sck  = (tid & 7) ^ (((tid >> 5) & 1) << 1);         // involution
  const ushort_t* gA = A  + (size_t)(row0 + srow) * KDIM + sck * 8;
  const ushort_t* gB = Bw + (size_t)(col0 + srow) * KDIM + sck * 8;
  char* ldsW = sm + wave * 1024;                                // wave-uniform

  f32x4 acc[8][4];
#pragma unroll
  for (int i = 0; i < 8; ++i)
#pragma unroll
    for (int j = 0; j < 4; ++j) {
      f32x4 z = {0.f, 0.f, 0.f, 0.f};
      acc[i][j] = z;
    }
  bf16x8 af[4][2], b0[2][2], b1[2][2];

// stage one 128-row half-tile (2 x global_load_lds of 8KB each)
#define STG(gbase, ktile, h, isB, s)                                          \
  do {                                                                        \
    const ushort_t* _g = (gbase) + (size_t)((h) * 128) * KDIM + (ktile) * 64; \
    char* _l = ldsW + (s) * 65536 + (isB) * 32768 + (h) * 16384;              \
    llds16(_g, _l);                                                           \
    llds16(_g + (size_t)64 * KDIM, _l + 8192);                                \
  } while (0)

#define BAR()                                                                 \
  do {                                                                        \
    __builtin_amdgcn_sched_barrier(0);                                        \
    asm volatile("" ::: "memory");                                            \
    __builtin_amdgcn_s_barrier();                                             \
    asm volatile("" ::: "memory");                                            \
    __builtin_amdgcn_sched_barrier(0);                                        \
  } while (0)

#define MQ(QM, QN, B)                                                         \
  do {                                                                        \
    __builtin_amdgcn_s_setprio(1);                                            \
    mfma_quad<QM, QN>(acc, af, B);                                            \
    __builtin_amdgcn_s_setprio(0);                                            \
  } while (0)

  // prologue: K-tiles 0 (slot0) and 1 (slot1) fully staged; wait for kt0 only
  STG(gA, 0, 0, 0, 0); STG(gA, 0, 1, 0, 0);
  STG(gB, 0, 0, 1, 0); STG(gB, 0, 1, 1, 0);
  STG(gA, 1, 0, 0, 1); STG(gA, 1, 1, 0, 1);
  STG(gB, 1, 0, 1, 1); STG(gB, 1, 1, 1, 1);
  asm volatile("s_waitcnt vmcnt(8)" ::: "memory");
  BAR();

#define KTILE(kt, s)                                                          \
  do {                                                                        \
    /* P1: A quad 0 + B pair 0 */                                             \
    load_frags<4>(af, sm + (s) * 65536 + aRegion + lfrag);                    \
    load_frags<2>(b0, sm + (s) * 65536 + bRegion + lfrag);                    \
    BAR();                                                                    \
    MQ(0, 0, b0);                                                             \
    BAR();                                                                    \
    /* P2: B pair 1 */                                                        \
    load_frags<2>(b1, sm + (s) * 65536 + bRegion + 4096 + lfrag);             \
    BAR();                                                                    \
    MQ(0, 1, b1);                                                             \
    BAR();                                                                    \
    /* P3: A quad 1; stage B halves of kt+2 (B last read at P2) */            \
    load_frags<4>(af, sm + (s) * 65536 + aRegion + 8192 + lfrag);             \
    if ((kt) + 2 < NIT) { STG(gB, (kt) + 2, 0, 1, s); STG(gB, (kt) + 2, 1, 1, s); } \
    BAR();                                                                    \
    MQ(1, 1, b1);                                                             \
    BAR();                                                                    \
    /* P4: stage A halves of kt+2 (A last read at P3); counted vmcnt */       \
    if ((kt) + 2 < NIT) { STG(gA, (kt) + 2, 0, 0, s); STG(gA, (kt) + 2, 1, 0, s); } \
    BAR();                                                                    \
    MQ(1, 0, b0);                                                             \
    if ((kt) + 2 < NIT)       asm volatile("s_waitcnt vmcnt(8)" ::: "memory"); \
    else if ((kt) + 2 == NIT) asm volatile("s_waitcnt vmcnt(0)" ::: "memory"); \
    BAR();                                                                    \
  } while (0)

#pragma unroll 1
  for (int kt = 0; kt < NIT; kt += 2) {
    KTILE(kt, 0);
    KTILE(kt + 1, 1);
  }
#undef KTILE
#undef MQ
#undef BAR
#undef STG

  // epilogue: C/D layout col=lane&15, row=quad*4+reg (verified m89/m91)
#pragma unroll
  for (int mi = 0; mi < 8; ++mi) {
#pragma unroll
    for (int ni = 0; ni < 4; ++ni) {
      const int row = row0 + wm * 128 + mi * 16 + quad * 4;
      const int col = col0 + wn * 64 + ni * 16 + lane16;
      float dv = 0.f;
      if (FUSE_SKIP) dv = Dvec[col];
#pragma unroll
      for (int r = 0; r < 4; ++r) {
        const size_t o = (size_t)(row + r) * NDIM + col;
        float val = acc[mi][ni][r];
        if (FUSE_SKIP) val = fmaf(dv, bf2f(skip_b[o]), val);
        if (OUT_BF16) ((ushort_t*)outv)[o] = f2bf(val);
        else          ((float*)outv)[o] = val;
      }
    }
  }
}

// ---------- chunked complex scan: h[t] = lam*h[t-1] + Bu[t], output Re(h) as bf16 ----------
// T=8192 split into 128 chunks of 64. Grid: BATCH*NCHUNK blocks x 128 threads,
// each thread owns 4 adjacent channels (ushort4 loads = 512B/wave, 4-way ILP).

__global__ __launch_bounds__(128)
void scan_chunks(const ushort_t* __restrict__ Bu, const float* __restrict__ lam,
                 float* __restrict__ S) {
  const int j = threadIdx.x * 4;                 // first of 4 channels
  const int c = blockIdx.x & (NCHUNK - 1);
  const int b = blockIdx.x >> 7;
  float lr[4], li[4], hr[4] = {0,0,0,0}, hi[4] = {0,0,0,0};
#pragma unroll
  for (int q = 0; q < 4; ++q) { lr[q] = lam[j + q]; li[q] = lam[512 + j + q]; }
  const ushort_t* p = Bu + ((size_t)(b * SEQ_LEN + c * CLEN)) * STATE_DIM + j;
#pragma unroll 4
  for (int t = 0; t < CLEN; ++t) {
    const ushort4 x4 = *(const ushort4*)(p + (size_t)t * STATE_DIM);
    const float x[4] = {bf2f(x4.x), bf2f(x4.y), bf2f(x4.z), bf2f(x4.w)};
#pragma unroll
    for (int q = 0; q < 4; ++q) {
      const float nr = fmaf(lr[q], hr[q], fmaf(-li[q], hi[q], x[q]));
      const float ni = fmaf(lr[q], hi[q], li[q] * hr[q]);
      hr[q] = nr; hi[q] = ni;
    }
  }
  const size_t o = (size_t)(b * NCHUNK + c) * STATE_DIM + j;
#pragma unroll
  for (int q = 0; q < 4; ++q) { S[o + q] = hr[q]; S[SOFF + o + q] = hi[q]; }
}

__global__ __launch_bounds__(512)
void scan_carry(const float* __restrict__ lam, const float* __restrict__ S,
                float* __restrict__ Hin) {
  const int idx = blockIdx.x * blockDim.x + threadIdx.x;  // 2048 = BATCH*512
  const int j = idx & 511, b = idx >> 9;
  const float pr = lam[1024 + j], pi = lam[1536 + j];  // lambda^CLEN
  float cr = 0.f, ci = 0.f;
  for (int c = 0; c < NCHUNK; ++c) {
    const size_t o = (size_t)(b * NCHUNK + c) * STATE_DIM + j;
    Hin[o] = cr; Hin[SOFF + o] = ci;
    const float sr = S[o], si = S[SOFF + o];
    const float nr = fmaf(pr, cr, fmaf(-pi, ci, sr));
    const float ni = fmaf(pr, ci, fmaf(pi, cr, si));
    cr = nr; ci = ni;
  }
}

__global__ __launch_bounds__(128)
void scan_final(const ushort_t* __restrict__ Bu, const float* __restrict__ lam,
                const float* __restrict__ Hin, ushort_t* __restrict__ h) {
  const int j = threadIdx.x * 4;
  const int c = blockIdx.x & (NCHUNK - 1);
  const int b = blockIdx.x >> 7;
  float lr[4], li[4], hr[4], hi[4];
#pragma unroll
  for (int q = 0; q < 4; ++q) { lr[q] = lam[j + q]; li[q] = lam[512 + j + q]; }
  const size_t so = (size_t)(b * NCHUNK + c) * STATE_DIM + j;
#pragma unroll
  for (int q = 0; q < 4; ++q) { hr[q] = Hin[so + q]; hi[q] = Hin[SOFF + so + q]; }
  const size_t base = ((size_t)(b * SEQ_LEN + c * CLEN)) * STATE_DIM + j;
#pragma unroll 4
  for (int t = 0; t < CLEN; ++t) {
    const ushort4 x4 = *(const ushort4*)(Bu + base + (size_t)t * STATE_DIM);
    const float x[4] = {bf2f(x4.x), bf2f(x4.y), bf2f(x4.z), bf2f(x4.w)};
    ushort4 o4;
#pragma unroll
    for (int q = 0; q < 4; ++q) {
      const float nr = fmaf(lr[q], hr[q], fmaf(-li[q], hi[q], x[q]));
      const float ni = fmaf(lr[q], hi[q], li[q] * hr[q]);
      hr[q] = nr; hi[q] = ni;
    }
    o4.x = f2bf(hr[0]); o4.y = f2bf(hr[1]); o4.z = f2bf(hr[2]); o4.w = f2bf(hr[3]);
    *(ushort4*)(h + base + (size_t)t * STATE_DIM) = o4;
  }
}

// ---------- launch ----------

extern "C" void kernel_launch(void* const* d_in, const int* in_sizes, int n_in,
                              void* d_out, int out_size, void* d_ws, size_t ws_size,
                              hipStream_t stream) {
  const float* u  = (const float*)d_in[0];  // (4, 8192, 1024)
  const float* ap = (const float*)d_in[1];  // (256,)
  const float* Bw = (const float*)d_in[2];  // (512, 1024)
  const float* Cw = (const float*)d_in[3];  // (1024, 512)
  const float* Dv = (const float*)d_in[4];  // (1024,)
  float* y = (float*)d_out;                 // (4, 8192, 1024)

  char* ws = (char*)d_ws;
  // workspace layout (bytes), total ~140.5 MB
  ushort_t* ub  = (ushort_t*)(ws + 0);            // u bf16:    67,108,864
  ushort_t* bwb = (ushort_t*)(ws + 67108864);     // B_w bf16:   1,048,576
  ushort_t* cwb = (ushort_t*)(ws + 68157440);     // C_w bf16:   1,048,576
  float*    lam = (float*)   (ws + 69206016);     // lambdas:        8,192
  ushort_t* Bu  = (ushort_t*)(ws + 69214208);     // Bu bf16:   33,554,432
  ushort_t* hb  = (ushort_t*)(ws + 102768640);    // h bf16:    33,554,432
  float*    S   = (float*)   (ws + 136323072);    // chunk states: 2,097,152
  float*    Hin = (float*)   (ws + 138420224);    // carries:      2,097,152

  // one-time opt-in for 128 KiB dynamic LDS (CUDA-compat path; no-op if not needed)
  static bool attr_done = false;
  if (!attr_done) {
    hipFuncSetAttribute(
        reinterpret_cast<const void*>(&gemm256<D_MODEL, STATE_DIM, true, false>),
        hipFuncAttributeMaxDynamicSharedMemorySize, 131072);
    hipFuncSetAttribute(
        reinterpret_cast<const void*>(&gemm256<STATE_DIM, D_MODEL, false, true>),
        hipFuncAttributeMaxDynamicSharedMemorySize, 131072);
    attr_done = true;
  }

  convert_f32_bf16<<<32768, 256, 0, stream>>>(u,  ub,  (M_TOTAL * D_MODEL) / 4);
  convert_f32_bf16<<<512,   256, 0, stream>>>(Bw, bwb, (STATE_DIM * D_MODEL) / 4);
  convert_f32_bf16<<<512,   256, 0, stream>>>(Cw, cwb, (D_MODEL * STATE_DIM) / 4);
  eigen_kernel<<<512, 64, 0, stream>>>(ap, lam);

  // Bu = u @ B_w^T : M=32768, N=512, K=1024  (bf16 out)
  gemm256<D_MODEL, STATE_DIM, true, false>
      <<<dim3(M_TOTAL / 256, STATE_DIM / 256), 512, 131072, stream>>>(
          ub, bwb, Bu, nullptr, nullptr);

  scan_chunks<<<BATCH * NCHUNK, 128, 0, stream>>>(Bu, lam, S);
  scan_carry<<<BATCH, 512, 0, stream>>>(lam, S, Hin);
  scan_final<<<BATCH * NCHUNK, 128, 0, stream>>>(Bu, lam, Hin, hb);

  // y = h @ C_w^T + D*u : M=32768, N=1024, K=512  (fp32 out, bf16 skip)
  gemm256<STATE_DIM, D_MODEL, false, true>
      <<<dim3(M_TOTAL / 256, D_MODEL / 256), 512, 131072, stream>>>(
          hb, cwb, y, ub, Dv);
}